// Round 13
// baseline (910.595 us; speedup 1.0000x reference)
//
#include <hip/hip_runtime.h>

#define NBINS 256
#define TPB 256
#define NCOPY 4       // one copy per wave
#define CSTRIDE 264   // 256 bins + dummy slot(256) + pad; copies bank-rotate by 8

typedef float f32x4 __attribute__((ext_vector_type(4)));

__global__ void zero_out_kernel(float* __restrict__ out) {
    out[threadIdx.x] = 0.0f;
}

// ---------------- hist kernel: R11 verbatim (76.3 us known) ----------------
__global__ __launch_bounds__(TPB) void hist_kernel(const float* __restrict__ x,
                                                   float* __restrict__ out,
                                                   int n) {
    __shared__ int lh[NCOPY * CSTRIDE];
    const int tid = threadIdx.x;
    int* __restrict__ myh = &lh[(tid >> 6) * CSTRIDE];

    for (int i = tid; i < NCOPY * CSTRIDE; i += TPB)
        lh[i] = 0;
    __syncthreads();

    const int gid    = blockIdx.x * TPB + tid;
    const int stride = gridDim.x * TPB;
    const int n4     = n >> 2;
    const f32x4* __restrict__ x4 = (const f32x4*)x;

#define PROC(f) {                                        \
        float _t = __builtin_fmaf((f), 32.0f, 128.0f);   \
        unsigned _u = (unsigned)_t;                      \
        _u = _u > 255u ? 255u : _u;                      \
        bool _ok = __builtin_fabsf(f) <= 4.0f;           \
        int _b = _ok ? (int)_u : 256;                    \
        atomicAdd(&myh[_b], 1);                          \
    }
#define PROC4(a) { PROC(a.x) PROC(a.y) PROC(a.z) PROC(a.w) }

    const int iters = n4 / (8 * stride);

    if (iters > 0) {
        int i = gid;
        f32x4 a = x4[i];
        f32x4 b = x4[i + stride];
        f32x4 c = x4[i + 2 * stride];
        f32x4 d = x4[i + 3 * stride];
        f32x4 e = x4[i + 4 * stride];
        f32x4 f = x4[i + 5 * stride];
        f32x4 g = x4[i + 6 * stride];
        f32x4 h = x4[i + 7 * stride];
        for (int t = 1; t < iters; ++t) {
            const int ni = i + 8 * stride;
            f32x4 na = x4[ni];
            f32x4 nb = x4[ni + stride];
            f32x4 nc = x4[ni + 2 * stride];
            f32x4 nd = x4[ni + 3 * stride];
            f32x4 ne = x4[ni + 4 * stride];
            f32x4 nf = x4[ni + 5 * stride];
            f32x4 ng = x4[ni + 6 * stride];
            f32x4 nh = x4[ni + 7 * stride];
            PROC4(a) PROC4(b) PROC4(c) PROC4(d)
            PROC4(e) PROC4(f) PROC4(g) PROC4(h)
            a = na; b = nb; c = nc; d = nd;
            e = ne; f = nf; g = ng; h = nh;
            i = ni;
        }
        PROC4(a) PROC4(b) PROC4(c) PROC4(d)
        PROC4(e) PROC4(f) PROC4(g) PROC4(h)
    }

    for (int i2 = iters * 8 * stride + gid; i2 < n4; i2 += stride) {
        f32x4 a = x4[i2];
        PROC4(a)
    }
    for (int j = (n4 << 2) + gid; j < n; j += stride) {
        float f2 = x[j];
        PROC(f2)
    }
#undef PROC4
#undef PROC

    __syncthreads();

    int s = lh[0 * CSTRIDE + tid] + lh[1 * CSTRIDE + tid] +
            lh[2 * CSTRIDE + tid] + lh[3 * CSTRIDE + tid];
    if (s)
        atomicAdd(&out[tid], (float)s);
}

// -------- probe 1: load-only x6 passes (per-pass = dur/6; hbm_gbps direct) ----
__global__ __launch_bounds__(TPB) void probe_load_kernel(const float* __restrict__ x,
                                                         int n) {
    const int tid    = threadIdx.x;
    const int gid    = blockIdx.x * TPB + tid;
    const int stride = gridDim.x * TPB;
    const int n4     = n >> 2;
    const f32x4* __restrict__ x4 = (const f32x4*)x;
    const int iters = n4 / (8 * stride);

    for (int p = 0; p < 6; ++p) {
        asm volatile("" ::: "memory");   // defeat cross-pass CSE of loads
        f32x4 acc = {0.f, 0.f, 0.f, 0.f};
        int i = gid;
        for (int t = 0; t < iters; ++t) {
            f32x4 a = x4[i];
            f32x4 b = x4[i + stride];
            f32x4 c = x4[i + 2 * stride];
            f32x4 d = x4[i + 3 * stride];
            f32x4 e = x4[i + 4 * stride];
            f32x4 f = x4[i + 5 * stride];
            f32x4 g = x4[i + 6 * stride];
            f32x4 h = x4[i + 7 * stride];
            acc += a + b + c + d + e + f + g + h;
            i += 8 * stride;
        }
        asm volatile("" :: "v"(acc.x), "v"(acc.y), "v"(acc.z), "v"(acc.w));
    }
}

// -------- probe 2: full hist structure, atomic -> asm sink, x4 passes --------
__global__ __launch_bounds__(TPB) void probe_nods_kernel(const float* __restrict__ x,
                                                         int n) {
    const int tid    = threadIdx.x;
    const int gid    = blockIdx.x * TPB + tid;
    const int stride = gridDim.x * TPB;
    const int n4     = n >> 2;
    const f32x4* __restrict__ x4 = (const f32x4*)x;
    const int iters = n4 / (8 * stride);

#define PROCN(f) {                                       \
        float _t = __builtin_fmaf((f), 32.0f, 128.0f);   \
        unsigned _u = (unsigned)_t;                      \
        _u = _u > 255u ? 255u : _u;                      \
        bool _ok = __builtin_fabsf(f) <= 4.0f;           \
        int _b = _ok ? (int)_u : 256;                    \
        asm volatile("" :: "v"(_b));                     \
    }
#define PROCN4(a) { PROCN(a.x) PROCN(a.y) PROCN(a.z) PROCN(a.w) }

    for (int p = 0; p < 4; ++p) {
        asm volatile("" ::: "memory");
        if (iters > 0) {
            int i = gid;
            f32x4 a = x4[i];
            f32x4 b = x4[i + stride];
            f32x4 c = x4[i + 2 * stride];
            f32x4 d = x4[i + 3 * stride];
            f32x4 e = x4[i + 4 * stride];
            f32x4 f = x4[i + 5 * stride];
            f32x4 g = x4[i + 6 * stride];
            f32x4 h = x4[i + 7 * stride];
            for (int t = 1; t < iters; ++t) {
                const int ni = i + 8 * stride;
                f32x4 na = x4[ni];
                f32x4 nb = x4[ni + stride];
                f32x4 nc = x4[ni + 2 * stride];
                f32x4 nd = x4[ni + 3 * stride];
                f32x4 ne = x4[ni + 4 * stride];
                f32x4 nf = x4[ni + 5 * stride];
                f32x4 ng = x4[ni + 6 * stride];
                f32x4 nh = x4[ni + 7 * stride];
                PROCN4(a) PROCN4(b) PROCN4(c) PROCN4(d)
                PROCN4(e) PROCN4(f) PROCN4(g) PROCN4(h)
                a = na; b = nb; c = nc; d = nd;
                e = ne; f = nf; g = ng; h = nh;
                i = ni;
            }
            PROCN4(a) PROCN4(b) PROCN4(c) PROCN4(d)
            PROCN4(e) PROCN4(f) PROCN4(g) PROCN4(h)
        }
    }
#undef PROCN4
#undef PROCN
}

// -------- probe 3: DS-atomic-only, x32 the hist atomic count --------
__global__ __launch_bounds__(TPB) void probe_ds_kernel(float* __restrict__ ws,
                                                       int steps) {
    __shared__ int lh[NCOPY * CSTRIDE];
    const int tid = threadIdx.x;
    int* __restrict__ myh = &lh[(tid >> 6) * CSTRIDE];

    for (int i = tid; i < NCOPY * CSTRIDE; i += TPB)
        lh[i] = 0;
    __syncthreads();

    unsigned u0 = (blockIdx.x * TPB + tid) * 2654435761u + 1u;
    unsigned u1 = u0 ^ 0x9E3779B9u;
    unsigned u2 = u0 + 0x85EBCA6Bu;
    unsigned u3 = u0 ^ 0xC2B2AE35u;
    for (int t = 0; t < steps; ++t) {
        u0 = u0 * 1664525u + 1013904223u;
        u1 = u1 * 1664525u + 1013904223u;
        u2 = u2 * 1664525u + 1013904223u;
        u3 = u3 * 1664525u + 1013904223u;
        atomicAdd(&myh[(u0 >> 10) & 255u], 1);
        atomicAdd(&myh[(u1 >> 10) & 255u], 1);
        atomicAdd(&myh[(u2 >> 10) & 255u], 1);
        atomicAdd(&myh[(u3 >> 10) & 255u], 1);
    }
    __syncthreads();

    int s = lh[tid] + lh[tid + 1024];
    asm volatile("" :: "v"(s));
    (void)ws;
}

extern "C" void kernel_launch(void* const* d_in, const int* in_sizes, int n_in,
                              void* d_out, int out_size, void* d_ws, size_t ws_size,
                              hipStream_t stream) {
    const float* x = (const float*)d_in[0];
    float* out = (float*)d_out;
    const int n = in_sizes[0];

    zero_out_kernel<<<1, NBINS, 0, stream>>>(out);

    int n4 = n >> 2;
    long long want = ((long long)n4 + (long long)TPB * 8 - 1) / ((long long)TPB * 8);
    int blocks = (int)(want < 1 ? 1 : (want > 2048 ? 2048 : want));
    hist_kernel<<<blocks, TPB, 0, stream>>>(x, out, n);

    // ---- instrumentation probes (timing-only; never touch d_out) ----
    probe_load_kernel<<<blocks, TPB, 0, stream>>>(x, n);
    probe_nods_kernel<<<blocks, TPB, 0, stream>>>(x, n);
    // hist does ~128 atomics/thread; x32 -> 4096/thread -> steps=1024
    int per_thread = (int)(((long long)n) / ((long long)blocks * TPB));
    int steps = (per_thread * 32) >> 2;
    if (steps < 1) steps = 1;
    probe_ds_kernel<<<blocks, TPB, 0, stream>>>((float*)d_ws, steps);
}

// Round 14
// 359.666 us; speedup vs baseline: 2.5318x; 2.5318x over previous
//
#include <hip/hip_runtime.h>

#define NBINS 256
#define TPB 256
#define NCOPY 16      // one copy per 16-lane group: splits same-bin lanes 4x
#define CSTRIDE 257   // bank-rotated copies: (c*257 + b) % 32 == (c + b) % 32

typedef float f32x4 __attribute__((ext_vector_type(4)));

__global__ void zero_out_kernel(float* __restrict__ out) {
    out[threadIdx.x] = 0.0f;
}

// ---- hist: R11 lean body + per-16-lane-group copies (same-address fix) ----
__global__ __launch_bounds__(TPB) void hist_kernel(const float* __restrict__ x,
                                                   float* __restrict__ out,
                                                   int n) {
    __shared__ int lh[NCOPY * CSTRIDE];   // 16448 B -> 8 blocks/CU, 32 waves/CU
    const int tid = threadIdx.x;
    int* __restrict__ myh = &lh[(tid >> 4) * CSTRIDE];

    for (int i = tid; i < NCOPY * CSTRIDE; i += TPB)
        lh[i] = 0;
    __syncthreads();

    const int gid    = blockIdx.x * TPB + tid;
    const int stride = gridDim.x * TPB;
    const int n4     = n >> 2;
    const f32x4* __restrict__ x4 = (const f32x4*)x;

#define PROC(f) {                                        \
        float _t = __builtin_fmaf((f), 32.0f, 128.0f);   \
        unsigned _u = (unsigned)_t;                      \
        _u = _u > 255u ? 255u : _u;                      \
        bool _ok = __builtin_fabsf(f) <= 4.0f;           \
        int _b = _ok ? (int)_u : 256;                    \
        atomicAdd(&myh[_b], 1);                          \
    }
#define PROC4(a) { PROC(a.x) PROC(a.y) PROC(a.z) PROC(a.w) }

    const int iters = n4 / (8 * stride);

    if (iters > 0) {
        int i = gid;
        f32x4 a = x4[i];
        f32x4 b = x4[i + stride];
        f32x4 c = x4[i + 2 * stride];
        f32x4 d = x4[i + 3 * stride];
        f32x4 e = x4[i + 4 * stride];
        f32x4 f = x4[i + 5 * stride];
        f32x4 g = x4[i + 6 * stride];
        f32x4 h = x4[i + 7 * stride];
        for (int t = 1; t < iters; ++t) {
            const int ni = i + 8 * stride;
            f32x4 na = x4[ni];
            f32x4 nb = x4[ni + stride];
            f32x4 nc = x4[ni + 2 * stride];
            f32x4 nd = x4[ni + 3 * stride];
            f32x4 ne = x4[ni + 4 * stride];
            f32x4 nf = x4[ni + 5 * stride];
            f32x4 ng = x4[ni + 6 * stride];
            f32x4 nh = x4[ni + 7 * stride];
            PROC4(a) PROC4(b) PROC4(c) PROC4(d)
            PROC4(e) PROC4(f) PROC4(g) PROC4(h)
            a = na; b = nb; c = nc; d = nd;
            e = ne; f = nf; g = ng; h = nh;
            i = ni;
        }
        PROC4(a) PROC4(b) PROC4(c) PROC4(d)
        PROC4(e) PROC4(f) PROC4(g) PROC4(h)
    }

    for (int i2 = iters * 8 * stride + gid; i2 < n4; i2 += stride) {
        f32x4 a = x4[i2];
        PROC4(a)
    }
    for (int j = (n4 << 2) + gid; j < n; j += stride) {
        float f2 = x[j];
        PROC(f2)
    }
#undef PROC4
#undef PROC

    __syncthreads();

    // flush: bin tid across 16 copies; reads are bank-rotated (2 lanes/bank,
    // free). One float atomic per bin per block: exact (< 2^24).
    int s = 0;
    #pragma unroll
    for (int c = 0; c < NCOPY; ++c)
        s += lh[c * CSTRIDE + tid];
    if (s)
        atomicAdd(&out[tid], (float)s);
}

// ---- mechanism probe: identical VALU, bins normal-like (mode=1) vs
// ---- uniform (mode=0). x8 hist atomic density. Same LDS layout as hist.
__global__ __launch_bounds__(TPB) void probe_ds_kernel(float* __restrict__ ws,
                                                       int steps, int mode) {
    __shared__ int lh[NCOPY * CSTRIDE];
    const int tid = threadIdx.x;
    int* __restrict__ myh = &lh[(tid >> 4) * CSTRIDE];

    for (int i = tid; i < NCOPY * CSTRIDE; i += TPB)
        lh[i] = 0;
    __syncthreads();

    unsigned u0 = (blockIdx.x * TPB + tid) * 2654435761u + 1u;
    unsigned u1 = u0 ^ 0x9E3779B9u;
    unsigned u2 = u0 + 0x85EBCA6Bu;
    unsigned u3 = u0 ^ 0xC2B2AE35u;

#define STEP(u) {                                                     \
        u = u * 1664525u + 1013904223u;                               \
        unsigned _s = (u & 255u) + ((u >> 8) & 255u) +                \
                      ((u >> 16) & 255u) + ((u >> 24) & 255u);        \
        unsigned _bin = mode ? (_s >> 2) : (_s & 255u);               \
        atomicAdd(&myh[_bin], 1);                                     \
    }
    for (int t = 0; t < steps; ++t) {
        STEP(u0) STEP(u1) STEP(u2) STEP(u3)
    }
#undef STEP
    __syncthreads();

    int s = lh[tid] + lh[tid + 2048];
    asm volatile("" :: "v"(s));
    (void)ws;
}

extern "C" void kernel_launch(void* const* d_in, const int* in_sizes, int n_in,
                              void* d_out, int out_size, void* d_ws, size_t ws_size,
                              hipStream_t stream) {
    const float* x = (const float*)d_in[0];
    float* out = (float*)d_out;
    const int n = in_sizes[0];

    zero_out_kernel<<<1, NBINS, 0, stream>>>(out);

    int n4 = n >> 2;
    long long want = ((long long)n4 + (long long)TPB * 8 - 1) / ((long long)TPB * 8);
    int blocks = (int)(want < 1 ? 1 : (want > 2048 ? 2048 : want));
    hist_kernel<<<blocks, TPB, 0, stream>>>(x, out, n);

    // ---- mechanism A/B probes (timing-only; never touch d_out) ----
    // x8 hist density: per_thread*8 atomics / 4 streams
    int per_thread = (int)(((long long)n) / ((long long)blocks * TPB));
    int steps = (per_thread * 8) >> 2;
    if (steps < 1) steps = 1;
    probe_ds_kernel<<<blocks, TPB, 0, stream>>>((float*)d_ws, steps, 1); // normal-like
    probe_ds_kernel<<<blocks, TPB, 0, stream>>>((float*)d_ws, steps, 0); // uniform
}

// Round 15
// 76.351 us; speedup vs baseline: 11.9264x; 4.7107x over previous
//
#include <hip/hip_runtime.h>

#define NBINS 256
#define TPB 256
#define NCOPY 16      // one copy per 16-lane group: splits same-bin chains 4x vs per-wave
#define CSTRIDE 257   // bank-rotated copies: (c*257 + b) % 32 == (c + b) % 32

typedef float f32x4 __attribute__((ext_vector_type(4)));

__global__ void zero_out_kernel(float* __restrict__ out) {
    out[threadIdx.x] = 0.0f;
}

// Lean branchless body (R11) + per-16-lane-group LDS copies (R14): 44 us.
// Mechanism (R13/R14 probes): DS-atomic cost is dominated by intra-wave
// same-ADDRESS RMW chains, not bank conflicts, not pipe throughput. 16-group
// copies split normal-data chains ~4x; once split, bin distribution is
// irrelevant (normal == uniform in the A/B probe). Load stream standalone
// (T_load, R13): ~39 us = 6.6 TB/s -- the read ceiling for this pattern.
__global__ __launch_bounds__(TPB) void hist_kernel(const float* __restrict__ x,
                                                   float* __restrict__ out,
                                                   int n) {
    __shared__ int lh[NCOPY * CSTRIDE];   // 16448 B -> 8 blocks/CU, 32 waves/CU
    const int tid = threadIdx.x;
    int* __restrict__ myh = &lh[(tid >> 4) * CSTRIDE];

    for (int i = tid; i < NCOPY * CSTRIDE; i += TPB)
        lh[i] = 0;
    __syncthreads();

    const int gid    = blockIdx.x * TPB + tid;
    const int stride = gridDim.x * TPB;
    const int n4     = n >> 2;
    const f32x4* __restrict__ x4 = (const f32x4*)x;

    // bin = trunc(fma(f,32,128)) == trunc((f+4)*32) up to one rounding at bin
    // edges (counts move <=1 bin for values within ~2^-16 of an edge -- far
    // inside the harness absmax threshold). cvt_u32 clamps negatives, min caps
    // at 255 (x==4 -> 256 -> 255); |f|<=4 check (abs modifier, NaN fails)
    // routes rejects to dummy slot 256 (never flushed).
#define PROC(f) {                                        \
        float _t = __builtin_fmaf((f), 32.0f, 128.0f);   \
        unsigned _u = (unsigned)_t;                      \
        _u = _u > 255u ? 255u : _u;                      \
        bool _ok = __builtin_fabsf(f) <= 4.0f;           \
        int _b = _ok ? (int)_u : 256;                    \
        atomicAdd(&myh[_b], 1);                          \
    }
#define PROC4(a) { PROC(a.x) PROC(a.y) PROC(a.z) PROC(a.w) }

    const int iters = n4 / (8 * stride);   // wave-uniform (4 for canonical shape)

    // 8 float4 loads in flight per wave, depth-2 software pipeline.
    if (iters > 0) {
        int i = gid;
        f32x4 a = x4[i];
        f32x4 b = x4[i + stride];
        f32x4 c = x4[i + 2 * stride];
        f32x4 d = x4[i + 3 * stride];
        f32x4 e = x4[i + 4 * stride];
        f32x4 f = x4[i + 5 * stride];
        f32x4 g = x4[i + 6 * stride];
        f32x4 h = x4[i + 7 * stride];
        for (int t = 1; t < iters; ++t) {
            const int ni = i + 8 * stride;
            f32x4 na = x4[ni];
            f32x4 nb = x4[ni + stride];
            f32x4 nc = x4[ni + 2 * stride];
            f32x4 nd = x4[ni + 3 * stride];
            f32x4 ne = x4[ni + 4 * stride];
            f32x4 nf = x4[ni + 5 * stride];
            f32x4 ng = x4[ni + 6 * stride];
            f32x4 nh = x4[ni + 7 * stride];
            PROC4(a) PROC4(b) PROC4(c) PROC4(d)
            PROC4(e) PROC4(f) PROC4(g) PROC4(h)
            a = na; b = nb; c = nc; d = nd;
            e = ne; f = nf; g = ng; h = nh;
            i = ni;
        }
        PROC4(a) PROC4(b) PROC4(c) PROC4(d)
        PROC4(e) PROC4(f) PROC4(g) PROC4(h)
    }

    // leftover float4s beyond the uniform region
    for (int i2 = iters * 8 * stride + gid; i2 < n4; i2 += stride) {
        f32x4 a = x4[i2];
        PROC4(a)
    }
    // scalar tail (n % 4 != 0 -- not hit for N=64M)
    for (int j = (n4 << 2) + gid; j < n; j += stride) {
        float f2 = x[j];
        PROC(f2)
    }
#undef PROC4
#undef PROC

    __syncthreads();

    // flush: bin tid across 16 copies; reads bank-rotate (2 lanes/bank, free).
    // One float atomic per bin per block: integer-valued < 2^24 -> exact,
    // order-independent -> deterministic.
    int s = 0;
    #pragma unroll
    for (int c = 0; c < NCOPY; ++c)
        s += lh[c * CSTRIDE + tid];
    if (s)
        atomicAdd(&out[tid], (float)s);
}

extern "C" void kernel_launch(void* const* d_in, const int* in_sizes, int n_in,
                              void* d_out, int out_size, void* d_ws, size_t ws_size,
                              hipStream_t stream) {
    const float* x = (const float*)d_in[0];
    float* out = (float*)d_out;
    const int n = in_sizes[0];

    // d_out is poisoned before timing and not re-zeroed between replays:
    // zero it ourselves every call (stream-ordered before hist).
    zero_out_kernel<<<1, NBINS, 0, stream>>>(out);

    int n4 = n >> 2;
    long long want = ((long long)n4 + (long long)TPB * 8 - 1) / ((long long)TPB * 8);
    int blocks = (int)(want < 1 ? 1 : (want > 2048 ? 2048 : want));
    hist_kernel<<<blocks, TPB, 0, stream>>>(x, out, n);
}